// Round 1
// 110.649 us; speedup vs baseline: 1.0050x; 1.0050x over previous
//
#include <hip/hip_runtime.h>
#include <stdint.h>

// inputs [B=64, T=256, D=1024] f32; tanh -> sequential dual-threshold
// integrate-and-fire scan over T per (b,d). 65536 sequences = 1024 waves
// = 4 waves/CU (structural, 1 wave/SIMD). Latency hiding: register
// TRIPLE-buffer with raw asm global loads + manual s_waitcnt vmcnt(N)
// that never drains to 0. Prefetch lead = 2 chunk-times (~2000 cyc)
// vs HBM latency ~900 cyc; the previous double-buffer lead (~1000 cyc)
// had zero margin over latency with no second wave/SIMD to cover it.
#define B_DIM 64
#define T_STEPS 256
#define D_DIM 1024
#define CT 16                   // timesteps per register chunk
#define CHUNKS (T_STEPS / CT)   // 16
#define TPB 256

// XLA/Eigen f32 tanh rational approximation — bit-exact vs jnp.tanh
// (verified rounds 1-2: absmax = 0.0). DO NOT change the FMA structure.
__device__ __forceinline__ float xla_tanhf(float x) {
    const float kClamp = 7.90531110763549805f;
    float xc = fminf(fmaxf(x, -kClamp), kClamp);
    float x2 = xc * xc;
    float p = __builtin_fmaf(x2, -2.76076847742355e-16f, 2.00018790482477e-13f);
    p = __builtin_fmaf(x2, p, -8.60467152213735e-11f);
    p = __builtin_fmaf(x2, p, 5.12229709037114e-08f);
    p = __builtin_fmaf(x2, p, 1.48572235717979e-05f);
    p = __builtin_fmaf(x2, p, 6.37261928875436e-04f);
    p = __builtin_fmaf(x2, p, 4.89352455891786e-03f);
    p = xc * p;
    float q = __builtin_fmaf(x2, 1.19825839466702e-06f, 1.18534705686654e-04f);
    q = __builtin_fmaf(x2, q, 2.26843463243900e-03f);
    q = __builtin_fmaf(x2, q, 4.89352518554385e-03f);
    float r = p / q;           // IEEE divide — required for bit-exactness
    return (fabsf(x) < 0.0004f) ? x : r;
}

// --- raw-asm pipeline building blocks -----------------------------------
// One load + advance voff by one timestep (D_DIM*4 = 4096 B). saddr form:
// addr = SGPR base + zext(voff); whole tensor is 64 MB so 32-bit offsets fit.
#define LD(i) "global_load_dword %" #i ", %16, %17\n\t" \
              "v_add_u32 %16, 0x1000, %16\n\t"

// Issue 16 loads for one chunk into buffer B (compiler never sees them as
// memory ops -> no auto-waitcnt; vmcnt tracked manually).
#define ISSUE16(B) asm volatile( \
    LD(0) LD(1) LD(2) LD(3) LD(4) LD(5) LD(6) LD(7) \
    LD(8) LD(9) LD(10) LD(11) LD(12) LD(13) LD(14) LD(15) \
    : "=v"(B[0]), "=v"(B[1]), "=v"(B[2]), "=v"(B[3]), \
      "=v"(B[4]), "=v"(B[5]), "=v"(B[6]), "=v"(B[7]), \
      "=v"(B[8]), "=v"(B[9]), "=v"(B[10]), "=v"(B[11]), \
      "=v"(B[12]), "=v"(B[13]), "=v"(B[14]), "=v"(B[15]), \
      "+v"(voffi) \
    : "s"(inp_u) : "memory")

// Wait until <= CNT vmem ops outstanding; "+v" on all 16 regs of the buffer
// we're about to read makes every use data-dependent on this wait (stops
// the scheduler hoisting tanh above it). vmcnt ops retire IN ORDER, so
// "outstanding <= N" == "everything older than the newest N has completed".
#define WAITBUF(B, CNT) asm volatile("s_waitcnt vmcnt(" CNT ")" \
    : "+v"(B[0]), "+v"(B[1]), "+v"(B[2]), "+v"(B[3]), \
      "+v"(B[4]), "+v"(B[5]), "+v"(B[6]), "+v"(B[7]), \
      "+v"(B[8]), "+v"(B[9]), "+v"(B[10]), "+v"(B[11]), \
      "+v"(B[12]), "+v"(B[13]), "+v"(B[14]), "+v"(B[15]) \
    :: "memory")

// 16 scan steps + 16 nontemporal stores (stores count toward vmcnt in
// issue order — accounted for in the WAITBUF constants).
#define COMPUTE16(B) \
    _Pragma("unroll") \
    for (int u = 0; u < CT; ++u) { \
        float r = xla_tanhf(B[u]); \
        v = __builtin_fmaf(r, 0.01f, v); \
        float sp = (v >= 1.0f)  ? 1.0f : 0.0f; \
        float sn = (v <= -1.0f) ? 1.0f : 0.0f; \
        v = (v - sp) + sn; \
        float o = (sp - sn) * 100.0f; \
        asm volatile("global_store_dword %0, %1, %2 nt\n\t" \
                     "v_add_u32 %0, 0x1000, %0" \
                     : "+v"(voffo) : "v"(o), "s"(outp_u) : "memory"); \
    }

// Steady-state chunk c (c in 2..13): issue L(c+2) into NXT, then wait for
// L(c) in CUR. VMEM issue order around this point:
//   ..., L(c) | S(c-2),16  L(c+1),16  S(c-1),16  L(c+2),16 | <wait here>
// Newest 48 = L(c+1)+S(c-1)+L(c+2)  ->  vmcnt(48) guarantees L(c) (and
// S(c-2), which sits just older) retired, while keeping TWO full chunks
// of loads in flight. Transients can brush the 6-bit vmcnt cap (63); HW
// micro-stalls issue there, which is harmless.
#define CHUNK3(NXT, CUR) do { ISSUE16(NXT); WAITBUF(CUR, "48"); COMPUTE16(CUR); } while (0)

__global__ __launch_bounds__(TPB)
void spike_scan_kernel(const float* __restrict__ in, float* __restrict__ out) {
    const int gid = blockIdx.x * blockDim.x + threadIdx.x;   // 0..65535
    const int b = gid >> 10;             // / D_DIM
    const int d = gid & (D_DIM - 1);     // % D_DIM
    const uint32_t base_bytes = ((uint32_t)b * (T_STEPS * D_DIM) + (uint32_t)d) * 4u;

    uint32_t voffi = base_bytes;         // running input byte offset (per-lane)
    uint32_t voffo = base_bytes;         // running output byte offset
    const uint64_t inp_u  = (uint64_t)in;
    const uint64_t outp_u = (uint64_t)out;

    float bufA[CT], bufB[CT], bufC[CT];
    float v = 0.0f;

    ISSUE16(bufA);                                    // L0
    ISSUE16(bufB);                                    // L1
    // chunk 0: issue L2; newer-than-L0 = L1(16)+L2(16) -> vmcnt(32)
    ISSUE16(bufC); WAITBUF(bufA, "32"); COMPUTE16(bufA);
    // chunk 1: issue L3; newer-than-L1 = L2+S0+L3 = 48 -> vmcnt(48)
    ISSUE16(bufA); WAITBUF(bufB, "48"); COMPUTE16(bufB);
    // chunks 2..13: rotation period 3. chunk c computes buf(c%3) and
    // issues L(c+2) into buf((c+2)%3) (freed at chunk c-1).
    #pragma unroll 1
    for (int c3 = 0; c3 < 4; ++c3) {
        CHUNK3(bufB, bufC);                           // chunks 2,5,8,11
        CHUNK3(bufC, bufA);                           // chunks 3,6,9,12
        CHUNK3(bufA, bufB);                           // chunks 4,7,10,13
    }
    // chunk 14 (computes C <- L14, issued at chunk 12): newer-than-L14 =
    // S12(16)+L15(16)+S13(16) = 48 -> vmcnt(48)
    WAITBUF(bufC, "48"); COMPUTE16(bufC);
    // chunk 15 (computes A <- L15, issued at chunk 13): newer-than-L15 =
    // S13(16)+S14(16) = 32 -> vmcnt(32)
    WAITBUF(bufA, "32"); COMPUTE16(bufA);
}

extern "C" void kernel_launch(void* const* d_in, const int* in_sizes, int n_in,
                              void* d_out, int out_size, void* d_ws, size_t ws_size,
                              hipStream_t stream) {
    const float* in = (const float*)d_in[0];
    float* out = (float*)d_out;
    dim3 block(TPB);
    dim3 grid((B_DIM * D_DIM) / TPB);    // 256 blocks, one 256-thread slice each
    spike_scan_kernel<<<grid, block, 0, stream>>>(in, out);
}